// Round 22
// baseline (273.092 us; speedup 1.0000x reference)
//
#include <hip/hip_runtime.h>
#include <math.h>

// CapsNet dynamic routing — MFMA sweeps; ALL intermediate reductions folded
// into the consuming sweep prologues.
//
// R21 = 112.2us, 9 launches. R22: drop reduce_p<P1>/reduce_p<P2> — sweep_m<2>
// reduces P1 inline (coalesced, unrolled, 50% occupancy hides latency —
// unlike R18's 1.2%-occ vupd), sweep_m<3> reduces P1+P2 inline. Same k-sum
// order -> bit-identical. Launches 9 -> 6. reduce_p<P3>+final_lite kept.
//
// x: [B=64, N=1152, Din=8], W: [C=128, N=1152, Din=8, Dout=16]
// out: [B=64, C=128, Dout=16]

typedef _Float16 half_t;
typedef _Float16 half8 __attribute__((ext_vector_type(8)));
typedef float f32x4 __attribute__((ext_vector_type(4)));

constexpr int NCAP = 1152;
constexpr int DIN  = 8;
constexpr int DOUT = 16;
constexpr int NCLS = 128;
constexpr int NB   = 64;

constexpr int CHM = 16;   // K-chunks per class -> 2048 sweep blocks

// ---------- MFMA path layout (float units) ----------
struct LM {
    static constexpr size_t XSH_OFF = 0;                              // x fp16 [n][b] 16B
    static constexpr size_t XSH_SZ  = (size_t)NCAP * NB * 4;
    static constexpr size_t W2T_OFF = XSH_OFF + XSH_SZ;               // W fp16 [c][o][k]
    static constexpr size_t W2T_SZ  = (size_t)NCLS * DOUT * NCAP * DIN / 2;
    static constexpr size_t P1_OFF  = W2T_OFF + W2T_SZ;
    static constexpr size_t P1_SZ   = (size_t)NCLS * CHM * DOUT * NB;
    static constexpr size_t P2_OFF  = P1_OFF + P1_SZ;
    static constexpr size_t P23_SZ  = (size_t)NCLS * CHM * (DOUT + 1) * NB;
    static constexpr size_t P3_OFF  = P2_OFF + P23_SZ;
    static constexpr size_t A3_OFF  = P3_OFF + P23_SZ;                // Acc3 [c][17][b]
    static constexpr size_t A23_SZ  = (size_t)NCLS * (DOUT + 1) * NB;
    static constexpr size_t TOTAL   = A3_OFF + A23_SZ;
};

// ---------- fp32 fallback layout (R9, proven) ----------
template<int CH> struct Layout {
    static constexpr size_t XS_OFF = 0;
    static constexpr size_t XS_SZ  = (size_t)NCAP * NB * DIN;
    static constexpr size_t P1_OFF = XS_OFF + XS_SZ;
    static constexpr size_t P1_SZ  = (size_t)NCLS * CH * DOUT * NB;
    static constexpr size_t P2_OFF = P1_OFF + P1_SZ;
    static constexpr size_t P23_SZ = (size_t)NCLS * CH * (DOUT + 1) * NB;
    static constexpr size_t P3_OFF = P2_OFF + P23_SZ;
    static constexpr size_t VA_OFF = P3_OFF + P23_SZ;
    static constexpr size_t V_SZ   = (size_t)NCLS * DOUT * NB;
    static constexpr size_t VB_OFF = VA_OFF + V_SZ;
    static constexpr size_t TOTAL  = VB_OFF + V_SZ;
};

#define WAITV(N) asm volatile("s_waitcnt vmcnt(" #N ")" ::: "memory")
#define SB() __builtin_amdgcn_sched_barrier(0)
#define AS1 __attribute__((address_space(1)))
#define AS3 __attribute__((address_space(3)))

__device__ __forceinline__ half8 bch8(const void* p) {
    return *reinterpret_cast<const half8*>(p);
}

// ---- prep_fused: part 1 = squash(x)->fp16 xsh[n][b]; part 2 = W->w2t fp16.
constexpr int XWORK = NCAP * NB;
constexpr int WWORK = NCLS * NCAP * DOUT;
__global__ __launch_bounds__(256) void prep_fused(const float* __restrict__ x,
                                                  const float* __restrict__ W,
                                                  float* __restrict__ xsh,
                                                  float* __restrict__ w2t) {
    const int t = blockIdx.x * 256 + threadIdx.x;
    if (t < XWORK) {
        const int n = t >> 6;
        const int b = t & 63;
        const float4* xp = reinterpret_cast<const float4*>(x + ((size_t)b * NCAP + n) * DIN);
        float4 a = xp[0], c4 = xp[1];
        float sq = a.x*a.x + a.y*a.y + a.z*a.z + a.w*a.w
                 + c4.x*c4.x + c4.y*c4.y + c4.z*c4.z + c4.w*c4.w;
        float sc = sq / ((1.0f + sq) * sqrtf(sq));
        half8 h = {(half_t)(a.x*sc),  (half_t)(a.y*sc),  (half_t)(a.z*sc),  (half_t)(a.w*sc),
                   (half_t)(c4.x*sc), (half_t)(c4.y*sc), (half_t)(c4.z*sc), (half_t)(c4.w*sc)};
        reinterpret_cast<half8*>(xsh)[t] = h;
    } else if (t < XWORK + WWORK) {
        const int u   = t - XWORK;
        const int c   = u / (NCAP * DOUT);
        const int rem = u % (NCAP * DOUT);
        const int n   = rem >> 4;
        const int o   = rem & 15;
        const float* src = W + ((size_t)(c * NCAP + n) * DIN) * DOUT + o;
        half8 h;
#pragma unroll
        for (int i = 0; i < DIN; ++i) h[i] = (half_t)src[i * DOUT];
        half_t* dst = reinterpret_cast<half_t*>(w2t) +
                      ((size_t)(c * DOUT + o) * NCAP + n) * DIN;
        *reinterpret_cast<half8*>(dst) = h;
    }
}

// ---- sweep_m: MFMA sweep. MODE 1: dense. MODE 2: V=V1 from inline-reduced P1.
// MODE 3: V=V1+v2 from inline-reduced P1,P2. Prologue array-free (rule #20);
// k-sum order = old reduce_p (ascending k) -> bit-identical results.
template<int MODE, int CH>
__global__ __launch_bounds__(256, 4) void sweep_m(const float* __restrict__ xsh,
                                                  const float* __restrict__ w2t,
                                                  float* __restrict__ P,
                                                  const float* __restrict__ P1in,
                                                  const float* __restrict__ P2in) {
    constexpr bool WEIGHTED = (MODE >= 2);
    constexpr int NPC = NCAP / CH;
    constexpr int KS  = NPC / 4;
    static_assert(KS * 4 == NPC, "geometry");

    const int bgid = blockIdx.x;     // = c*CH + ch
    const int c    = bgid / CH;
    const int ch   = bgid % CH;
    const int lane = threadIdx.x & 63;
    const int w    = threadIdx.x >> 6;
    const int grp  = lane >> 4;
    const int li   = lane & 15;
    const int bidx = w * 16 + li;

    const half_t* wb = reinterpret_cast<const half_t*>(w2t) +
                       (size_t)(c * DOUT + li) * (NCAP * DIN);
    const half_t* xb = reinterpret_cast<const half_t*>(xsh);
    const int nb0 = ch * NPC;

    // prologue: reduce P over k inline and rebuild V — scalars + addr arith only
    float Vf[4];
    if (WEIGHTED) {
        const float* p1 = P1in + (size_t)c * CH * DOUT * NB + bidx;
        constexpr float invn = 1.0f / (float)NCAP;
        float sq1 = 0.f;
#pragma unroll
        for (int o = 0; o < DOUT; ++o) {
            float acc = 0.f;
#pragma unroll
            for (int k = 0; k < CH; ++k)
                acc += p1[((size_t)k * DOUT + o) * NB];
            acc *= invn;
            sq1 = fmaf(acc, acc, sq1);
        }
        const float sc1 = sq1 / ((1.0f + sq1) * sqrtf(sq1));
#pragma unroll
        for (int r = 0; r < 4; ++r) {
            float acc = 0.f;
#pragma unroll
            for (int k = 0; k < CH; ++k)
                acc += p1[((size_t)k * DOUT + (grp * 4 + r)) * NB];
            Vf[r] = acc * invn * sc1;
        }
        if (MODE == 3) {
            const float* p2 = P2in + (size_t)c * CH * (DOUT + 1) * NB + bidx;
            float Zt = 0.f;
#pragma unroll
            for (int k = 0; k < CH; ++k)
                Zt += p2[((size_t)k * (DOUT + 1) + DOUT) * NB];
            const float rz = 1.0f / Zt;
            float sq2 = 0.f;
#pragma unroll
            for (int o = 0; o < DOUT; ++o) {
                float acc = 0.f;
#pragma unroll
                for (int k = 0; k < CH; ++k)
                    acc += p2[((size_t)k * (DOUT + 1) + o) * NB];
                acc *= rz;
                sq2 = fmaf(acc, acc, sq2);
            }
            const float sc2 = sq2 / ((1.0f + sq2) * sqrtf(sq2));
#pragma unroll
            for (int r = 0; r < 4; ++r) {
                float acc = 0.f;
#pragma unroll
                for (int k = 0; k < CH; ++k)
                    acc += p2[((size_t)k * (DOUT + 1) + (grp * 4 + r)) * NB];
                Vf[r] = fmaf(acc * rz, sc2, Vf[r]);
            }
        }
    }

    auto LDA = [&](int ks) -> half8 {
        return bch8(wb + (size_t)(nb0 + ks * 4 + grp) * DIN);
    };
    auto LDX = [&](int ks) -> half8 {
        return bch8(xb + ((size_t)(nb0 + ks * 4 + grp) * NB + bidx) * DIN);
    };

    f32x4 S = {0.f, 0.f, 0.f, 0.f};
    float Z = 0.f;
    const half8 hz = {};
    const f32x4 fz = {0.f, 0.f, 0.f, 0.f};

    half8 a_c = LDA(0), x_c = LDX(0);
    half8 a_n = a_c, x_n = x_c;

#pragma unroll 1
    for (int ks = 0; ks < KS; ++ks) {
        if (ks + 1 < KS) { a_n = LDA(ks + 1); x_n = LDX(ks + 1); }
        if (!WEIGHTED) {
            S = __builtin_amdgcn_mfma_f32_16x16x32_f16(a_c, x_c, S, 0, 0, 0);
        } else {
            f32x4 u0 = __builtin_amdgcn_mfma_f32_16x16x32_f16(a_c, (grp == 0) ? x_c : hz, fz, 0, 0, 0);
            f32x4 u1 = __builtin_amdgcn_mfma_f32_16x16x32_f16(a_c, (grp == 1) ? x_c : hz, fz, 0, 0, 0);
            f32x4 u2 = __builtin_amdgcn_mfma_f32_16x16x32_f16(a_c, (grp == 2) ? x_c : hz, fz, 0, 0, 0);
            f32x4 u3 = __builtin_amdgcn_mfma_f32_16x16x32_f16(a_c, (grp == 3) ? x_c : hz, fz, 0, 0, 0);

            float p0 = u0[0] * Vf[0], p1 = u1[0] * Vf[0],
                  p2 = u2[0] * Vf[0], p3 = u3[0] * Vf[0];
#pragma unroll
            for (int r = 1; r < 4; ++r) {
                p0 = fmaf(u0[r], Vf[r], p0);
                p1 = fmaf(u1[r], Vf[r], p1);
                p2 = fmaf(u2[r], Vf[r], p2);
                p3 = fmaf(u3[r], Vf[r], p3);
            }
            p0 += __shfl_xor(p0, 16); p1 += __shfl_xor(p1, 16);
            p2 += __shfl_xor(p2, 16); p3 += __shfl_xor(p3, 16);
            p0 += __shfl_xor(p0, 32); p1 += __shfl_xor(p1, 32);
            p2 += __shfl_xor(p2, 32); p3 += __shfl_xor(p3, 32);

            const float g0 = __expf(p0);
            const float g1 = __expf(p1);
            const float g2 = __expf(p2);
            const float g3 = __expf(p3);
#pragma unroll
            for (int r = 0; r < 4; ++r) {
                float s = S[r];
                s = fmaf(g0, u0[r], s);
                s = fmaf(g1, u1[r], s);
                s = fmaf(g2, u2[r], s);
                s = fmaf(g3, u3[r], s);
                S[r] = s;
            }
            Z += (g0 + g1) + (g2 + g3);
        }
        a_c = a_n; x_c = x_n;
    }

    if (!WEIGHTED) {
#pragma unroll
        for (int r = 0; r < 4; ++r)
            P[((size_t)bgid * DOUT + (grp * 4 + r)) * NB + bidx] = S[r];
    } else {
#pragma unroll
        for (int r = 0; r < 4; ++r)
            P[((size_t)bgid * (DOUT + 1) + (grp * 4 + r)) * NB + bidx] = S[r];
        if (grp == 0)
            P[((size_t)bgid * (DOUT + 1) + DOUT) * NB + bidx] = Z;
    }
}

// ---- reduce_p: stage-1 merge for P3 only. Block = one (c, slot); lane = b.
template<int SLOTS, int CH>
__global__ __launch_bounds__(64) void reduce_p(const float* __restrict__ P,
                                               float* __restrict__ Acc) {
    const int blk  = blockIdx.x;          // c*SLOTS + slot
    const int c    = blk / SLOTS;
    const int slot = blk % SLOTS;
    const int b    = threadIdx.x;
    const float* base = P + ((size_t)c * CH * SLOTS + slot) * NB + b;
    float acc = 0.f;
#pragma unroll
    for (int k = 0; k < CH; ++k) acc += base[(size_t)k * SLOTS * NB];
    Acc[(size_t)blk * NB + b] = acc;
}

// ---- final_lite: Acc3 -> v3, leaky^2, per-batch normalize
__global__ __launch_bounds__(256) void final_lite(const float* __restrict__ Acc3,
                                                  float* __restrict__ out) {
    const int b    = blockIdx.x;
    const int tid  = threadIdx.x;
    const int c    = tid >> 1;
    const int half = tid & 1;
    const float* base = Acc3 + (size_t)c * (DOUT + 1) * NB + b;

    const float rz = 1.0f / base[(size_t)DOUT * NB];

    float s[8];
    float sqh = 0.f;
#pragma unroll
    for (int j = 0; j < 8; ++j) {
        float v = base[(size_t)(half * 8 + j) * NB] * rz;
        s[j] = v;
        sqh += v * v;
    }
    const float sq = sqh + __shfl_xor(sqh, 1);
    const float sc = sq / ((1.0f + sq) * sqrtf(sq));

    float val[8];
    float ps = 0.f;
#pragma unroll
    for (int j = 0; j < 8; ++j) {
        const float v = s[j] * sc;
        const float l = v > 0.f ? v : 0.01f * v;
        val[j] = l * l;
        ps += val[j];
    }
#pragma unroll
    for (int off = 1; off < 64; off <<= 1) ps += __shfl_xor(ps, off);
    __shared__ float wsum[4];
    if ((tid & 63) == 0) wsum[tid >> 6] = ps;
    __syncthreads();
    const float inv = 1.0f / (wsum[0] + wsum[1] + wsum[2] + wsum[3]);
#pragma unroll
    for (int j = 0; j < 8; ++j)
        out[((size_t)b * NCLS + c) * DOUT + half * 8 + j] = val[j] * inv;
}

// ================= fp32 fallback path (R9, proven) =================
constexpr int NW        = 8;
constexpr int SWEEP_BLK = NW * 64;
constexpr int STG       = 4096;

__global__ __launch_bounds__(256) void prep_kernel(const float* __restrict__ x,
                                                   float* __restrict__ xs) {
    const int g = blockIdx.x * 256 + threadIdx.x;
    const int n = g >> 6;
    const int b = g & 63;
    const float4* xp = reinterpret_cast<const float4*>(x + ((size_t)b * NCAP + n) * DIN);
    float4 a = xp[0], c4 = xp[1];
    float sq = a.x*a.x + a.y*a.y + a.z*a.z + a.w*a.w
             + c4.x*c4.x + c4.y*c4.y + c4.z*c4.z + c4.w*c4.w;
    float sc = sq / ((1.0f + sq) * sqrtf(sq));
    float4 o0 = {a.x*sc,  a.y*sc,  a.z*sc,  a.w*sc};
    float4 o1 = {c4.x*sc, c4.y*sc, c4.z*sc, c4.w*sc};
    float4* op = reinterpret_cast<float4*>(xs + (size_t)g * DIN);
    op[0] = o0;
    op[1] = o1;
}

template<bool WEIGHTED, int CH>
__global__ __launch_bounds__(SWEEP_BLK, 2) void sweep_kernel(const float* __restrict__ xs,
                                                             const float* __restrict__ W,
                                                             float* __restrict__ P,
                                                             const float* __restrict__ vbuf) {
    constexpr int NPC    = NCAP / CH;
    constexpr int NPW    = NPC / NW;
    constexpr int NPAIRS = NPW / 2;

    const int bg = blockIdx.x;
    const int c  = bg / CH;
    const int ch = bg % CH;
    const int b  = threadIdx.x & 63;
    const int w  = threadIdx.x >> 6;

    __shared__ __align__(16) char smem[NW * (DOUT + 1) * NB * 4];

    float V[DOUT];
    if (WEIGHTED) {
        const float* vb = vbuf + (size_t)c * DOUT * NB + b;
#pragma unroll
        for (int o = 0; o < DOUT; ++o) V[o] = vb[o * NB];
    }

    float S[DOUT];
#pragma unroll
    for (int o = 0; o < DOUT; ++o) S[o] = 0.f;
    float Z = 0.f;

    const int n0 = ch * NPC + w * NPW;
    const char* wsrc = (const char*)W + ((size_t)c * NCAP + n0) * 512;
    char* mybuf = smem + w * STG;

    auto STAGE = [&](int p) {
        __builtin_amdgcn_global_load_lds(
            (const AS1 void*)(wsrc + (size_t)p * 1024 + b * 16),
            (AS3 void*)(mybuf + (p & 3) * 1024), 16, 0, 0);
    };
    auto XROW = [&](int row, float4& xa, float4& xb) {
        const float4* xp = reinterpret_cast<const float4*>(
            xs + ((size_t)(n0 + row) * NB + b) * DIN);
        xa = xp[0];
        xb = xp[1];
    };
    auto ROW = [&](int p, int r, float4 xa, float4 xb) {
        const float4* wl = reinterpret_cast<const float4*>(mybuf + (p & 3) * 1024 + r * 512);
        const float xv[DIN] = {xa.x, xa.y, xa.z, xa.w, xb.x, xb.y, xb.z, xb.w};
        if (!WEIGHTED) {
#pragma unroll
            for (int i = 0; i < DIN; ++i) {
                float4 q0 = wl[i*4+0], q1 = wl[i*4+1], q2 = wl[i*4+2], q3 = wl[i*4+3];
                const float xi = xv[i];
                S[ 0]=fmaf(xi,q0.x,S[ 0]); S[ 1]=fmaf(xi,q0.y,S[ 1]);
                S[ 2]=fmaf(xi,q0.z,S[ 2]); S[ 3]=fmaf(xi,q0.w,S[ 3]);
                S[ 4]=fmaf(xi,q1.x,S[ 4]); S[ 5]=fmaf(xi,q1.y,S[ 5]);
                S[ 6]=fmaf(xi,q1.z,S[ 6]); S[ 7]=fmaf(xi,q1.w,S[ 7]);
                S[ 8]=fmaf(xi,q2.x,S[ 8]); S[ 9]=fmaf(xi,q2.y,S[ 9]);
                S[10]=fmaf(xi,q2.z,S[10]); S[11]=fmaf(xi,q2.w,S[11]);
                S[12]=fmaf(xi,q3.x,S[12]); S[13]=fmaf(xi,q3.y,S[13]);
                S[14]=fmaf(xi,q3.z,S[14]); S[15]=fmaf(xi,q3.w,S[15]);
            }
        } else {
            float u[DOUT];
#pragma unroll
            for (int o = 0; o < DOUT; ++o) u[o] = 0.f;
#pragma unroll
            for (int i = 0; i < DIN; ++i) {
                float4 q0 = wl[i*4+0], q1 = wl[i*4+1], q2 = wl[i*4+2], q3 = wl[i*4+3];
                const float xi = xv[i];
                u[ 0]=fmaf(xi,q0.x,u[ 0]); u[ 1]=fmaf(xi,q0.y,u[ 1]);
                u[ 2]=fmaf(xi,q0.z,u[ 2]); u[ 3]=fmaf(xi,q0.w,u[ 3]);
                u[ 4]=fmaf(xi,q1.x,u[ 4]); u[ 5]=fmaf(xi,q1.y,u[ 5]);
                u[ 6]=fmaf(xi,q1.z,u[ 6]); u[ 7]=fmaf(xi,q1.w,u[ 7]);
                u[ 8]=fmaf(xi,q2.x,u[ 8]); u[ 9]=fmaf(xi,q2.y,u[ 9]);
                u[10]=fmaf(xi,q2.z,u[10]); u[11]=fmaf(xi,q2.w,u[11]);
                u[12]=fmaf(xi,q3.x,u[12]); u[13]=fmaf(xi,q3.y,u[13]);
                u[14]=fmaf(xi,q3.z,u[14]); u[15]=fmaf(xi,q3.w,u[15]);
            }
            float bd = 0.f;
#pragma unroll
            for (int o = 0; o < DOUT; ++o) bd = fmaf(u[o], V[o], bd);
            const float g = __expf(bd);
            Z += g;
#pragma unroll
            for (int o = 0; o < DOUT; ++o) S[o] = fmaf(g, u[o], S[o]);
        }
    };

    STAGE(0); SB();
    STAGE(1); SB();
    float4 ca0, ca1, cb0, cb1, na0, na1, nb0, nb1;
    XROW(0, ca0, ca1);
    XROW(1, cb0, cb1);
    SB();

#pragma unroll 1
    for (int p = 0; p < NPAIRS; ++p) {
        if (p + 2 < NPAIRS) STAGE(p + 2);
        SB();
        if (p + 1 < NPAIRS) {
            XROW(2 * (p + 1),     na0, na1);
            XROW(2 * (p + 1) + 1, nb0, nb1);
        }
        SB();
        if (p < NPAIRS - 2)       { WAITV(5); }
        else if (p == NPAIRS - 2) { WAITV(4); }
        else                      { WAITV(0); }
        SB();
        ROW(p, 0, ca0, ca1);
        ROW(p, 1, cb0, cb1);
        ca0 = na0; ca1 = na1; cb0 = nb0; cb1 = nb1;
    }

    __syncthreads();
    float (*red)[DOUT + 1][NB] = reinterpret_cast<float (*)[DOUT + 1][NB]>(smem);
#pragma unroll
    for (int o = 0; o < DOUT; ++o) red[w][o][b] = S[o];
    red[w][DOUT][b] = Z;
    __syncthreads();
    for (int idx = threadIdx.x; idx < (DOUT + 1) * NB; idx += SWEEP_BLK) {
        const int slot = idx >> 6;
        const int bb   = idx & 63;
        float acc = 0.f;
#pragma unroll
        for (int k = 0; k < NW; ++k) acc += red[k][slot][bb];
        if (!WEIGHTED) {
            if (slot < DOUT)
                P[((size_t)bg * DOUT + slot) * NB + bb] = acc;
        } else {
            P[((size_t)bg * (DOUT + 1) + slot) * NB + bb] = acc;
        }
    }
}

template<int MODE, int CH>
__global__ __launch_bounds__(64) void vupd_kernel(const float* __restrict__ P,
                                                  const float* __restrict__ vin,
                                                  float* __restrict__ vout) {
    const int c = blockIdx.x;
    const int b = threadIdx.x;

    float s[DOUT];
    float sq = 0.f;
    if (MODE == 1) {
#pragma unroll
        for (int o = 0; o < DOUT; ++o) {
            float acc = 0.f;
#pragma unroll
            for (int k = 0; k < CH; ++k)
                acc += P[(((size_t)c * CH + k) * DOUT + o) * NB + b];
            acc *= (1.0f / (float)NCAP);
            s[o] = acc;
            sq += acc * acc;
        }
    } else {
        float Zt = 0.f;
#pragma unroll
        for (int k = 0; k < CH; ++k)
            Zt += P[(((size_t)c * CH + k) * (DOUT + 1) + DOUT) * NB + b];
        const float rz = 1.0f / Zt;
#pragma unroll
        for (int o = 0; o < DOUT; ++o) {
            float acc = 0.f;
#pragma unroll
            for (int k = 0; k < CH; ++k)
                acc += P[(((size_t)c * CH + k) * (DOUT + 1) + o) * NB + b];
            acc *= rz;
            s[o] = acc;
            sq += acc * acc;
        }
    }
    const float sc = sq / ((1.0f + sq) * sqrtf(sq));
#pragma unroll
    for (int o = 0; o < DOUT; ++o) {
        float v = s[o] * sc;
        if (MODE == 2) v += vin[((size_t)c * DOUT + o) * NB + b];
        vout[((size_t)c * DOUT + o) * NB + b] = v;
    }
}

template<int CH>
__global__ __launch_bounds__(256) void final_kernel(const float* __restrict__ P3,
                                                    float* __restrict__ out) {
    const int b    = blockIdx.x;
    const int tid  = threadIdx.x;
    const int c    = tid >> 1;
    const int half = tid & 1;

    float Zt = 0.f;
#pragma unroll
    for (int k = 0; k < CH; ++k)
        Zt += P3[(((size_t)c * CH + k) * (DOUT + 1) + DOUT) * NB + b];
    const float rz = 1.0f / Zt;

    float s[8];
    float sqh = 0.f;
#pragma unroll
    for (int j = 0; j < 8; ++j) {
        const int o = half * 8 + j;
        float acc = 0.f;
#pragma unroll
        for (int k = 0; k < CH; ++k)
            acc += P3[(((size_t)c * CH + k) * (DOUT + 1) + o) * NB + b];
        acc *= rz;
        s[j] = acc;
        sqh += acc * acc;
    }
    const float sq = sqh + __shfl_xor(sqh, 1);
    const float sc = sq / ((1.0f + sq) * sqrtf(sq));

    float val[8];
    float ps = 0.f;
#pragma unroll
    for (int j = 0; j < 8; ++j) {
        const float v = s[j] * sc;
        const float l = v > 0.f ? v : 0.01f * v;
        val[j] = l * l;
        ps += val[j];
    }
#pragma unroll
    for (int off = 1; off < 64; off <<= 1) ps += __shfl_xor(ps, off);
    __shared__ float wsum[4];
    if ((tid & 63) == 0) wsum[tid >> 6] = ps;
    __syncthreads();
    const float inv = 1.0f / (wsum[0] + wsum[1] + wsum[2] + wsum[3]);
#pragma unroll
    for (int j = 0; j < 8; ++j)
        out[((size_t)b * NCLS + c) * DOUT + half * 8 + j] = val[j] * inv;
}

template<int CH>
static void run_f32(const float* x, const float* W, float* out, float* ws,
                    hipStream_t stream) {
    using L = Layout<CH>;
    float* xs = ws + L::XS_OFF;
    float* P1 = ws + L::P1_OFF;
    float* P2 = ws + L::P2_OFF;
    float* P3 = ws + L::P3_OFF;
    float* VA = ws + L::VA_OFF;
    float* VB = ws + L::VB_OFF;

    hipLaunchKernelGGL(prep_kernel, dim3(NCAP * NB / 256), dim3(256), 0, stream, x, xs);
    hipLaunchKernelGGL((sweep_kernel<false, CH>), dim3(NCLS * CH), dim3(SWEEP_BLK), 0,
                       stream, xs, W, P1, nullptr);
    hipLaunchKernelGGL((vupd_kernel<1, CH>), dim3(NCLS), dim3(64), 0, stream,
                       P1, nullptr, VA);
    hipLaunchKernelGGL((sweep_kernel<true, CH>), dim3(NCLS * CH), dim3(SWEEP_BLK), 0,
                       stream, xs, W, P2, VA);
    hipLaunchKernelGGL((vupd_kernel<2, CH>), dim3(NCLS), dim3(64), 0, stream,
                       P2, VA, VB);
    hipLaunchKernelGGL((sweep_kernel<true, CH>), dim3(NCLS * CH), dim3(SWEEP_BLK), 0,
                       stream, xs, W, P3, VB);
    hipLaunchKernelGGL((final_kernel<CH>), dim3(NB), dim3(256), 0, stream, P3, out);
}

extern "C" void kernel_launch(void* const* d_in, const int* in_sizes, int n_in,
                              void* d_out, int out_size, void* d_ws, size_t ws_size,
                              hipStream_t stream) {
    const float* x = (const float*)d_in[0];
    const float* W = (const float*)d_in[1];
    float* out = (float*)d_out;
    float* ws  = (float*)d_ws;

    if (ws_size >= LM::TOTAL * sizeof(float)) {
        float* xsh = ws + LM::XSH_OFF;
        float* w2t = ws + LM::W2T_OFF;
        float* P1  = ws + LM::P1_OFF;
        float* P2  = ws + LM::P2_OFF;
        float* P3  = ws + LM::P3_OFF;
        float* A3  = ws + LM::A3_OFF;

        hipLaunchKernelGGL(prep_fused, dim3((XWORK + WWORK + 255) / 256), dim3(256), 0,
                           stream, x, W, xsh, w2t);
        hipLaunchKernelGGL((sweep_m<1, CHM>), dim3(NCLS * CHM), dim3(256), 0,
                           stream, xsh, w2t, P1, nullptr, nullptr);
        hipLaunchKernelGGL((sweep_m<2, CHM>), dim3(NCLS * CHM), dim3(256), 0,
                           stream, xsh, w2t, P2, P1, nullptr);
        hipLaunchKernelGGL((sweep_m<3, CHM>), dim3(NCLS * CHM), dim3(256), 0,
                           stream, xsh, w2t, P3, P1, P2);
        hipLaunchKernelGGL((reduce_p<DOUT + 1, CHM>), dim3(NCLS * (DOUT + 1)), dim3(64), 0,
                           stream, P3, A3);
        hipLaunchKernelGGL(final_lite, dim3(NB), dim3(256), 0, stream, A3, out);
    } else if (ws_size >= Layout<8>::TOTAL * sizeof(float)) {
        run_f32<8>(x, W, out, ws, stream);
    } else {
        run_f32<4>(x, W, out, ws, stream);
    }
}

// Round 23
// 112.041 us; speedup vs baseline: 2.4374x; 2.4374x over previous
//
#include <hip/hip_runtime.h>
#include <math.h>

// CapsNet dynamic routing — MFMA sweeps + wide two-stage reduction (R21, best).
//
// R22 post-mortem: folding reduce_p into sweep prologues amplified reduction
// traffic 16x (each ch-block re-read the whole class slice; FETCH 21->112MB,
// sweeps 179us). Reverted to R21 verbatim: sweeps + reduce_p (each P element
// read once, wide) + vupd_lite/final_lite. 112.15us proven.
//
// x: [B=64, N=1152, Din=8], W: [C=128, N=1152, Din=8, Dout=16]
// out: [B=64, C=128, Dout=16]

typedef _Float16 half_t;
typedef _Float16 half8 __attribute__((ext_vector_type(8)));
typedef float f32x4 __attribute__((ext_vector_type(4)));

constexpr int NCAP = 1152;
constexpr int DIN  = 8;
constexpr int DOUT = 16;
constexpr int NCLS = 128;
constexpr int NB   = 64;

constexpr int CHM = 16;   // K-chunks per class -> 2048 sweep blocks

// ---------- MFMA path layout (float units) ----------
struct LM {
    static constexpr size_t XSH_OFF = 0;                              // x fp16 [n][b] 16B
    static constexpr size_t XSH_SZ  = (size_t)NCAP * NB * 4;
    static constexpr size_t W2T_OFF = XSH_OFF + XSH_SZ;               // W fp16 [c][o][k]
    static constexpr size_t W2T_SZ  = (size_t)NCLS * DOUT * NCAP * DIN / 2;
    static constexpr size_t P1_OFF  = W2T_OFF + W2T_SZ;
    static constexpr size_t P1_SZ   = (size_t)NCLS * CHM * DOUT * NB;
    static constexpr size_t P2_OFF  = P1_OFF + P1_SZ;
    static constexpr size_t P23_SZ  = (size_t)NCLS * CHM * (DOUT + 1) * NB;
    static constexpr size_t P3_OFF  = P2_OFF + P23_SZ;
    static constexpr size_t A1_OFF  = P3_OFF + P23_SZ;                // Acc1 [c][16][b]
    static constexpr size_t A1_SZ   = (size_t)NCLS * DOUT * NB;
    static constexpr size_t A2_OFF  = A1_OFF + A1_SZ;                 // Acc2 [c][17][b]
    static constexpr size_t A23_SZ  = (size_t)NCLS * (DOUT + 1) * NB;
    static constexpr size_t A3_OFF  = A2_OFF + A23_SZ;
    static constexpr size_t TOTAL   = A3_OFF + A23_SZ;
};

// ---------- fp32 fallback layout (R9, proven) ----------
template<int CH> struct Layout {
    static constexpr size_t XS_OFF = 0;
    static constexpr size_t XS_SZ  = (size_t)NCAP * NB * DIN;
    static constexpr size_t P1_OFF = XS_OFF + XS_SZ;
    static constexpr size_t P1_SZ  = (size_t)NCLS * CH * DOUT * NB;
    static constexpr size_t P2_OFF = P1_OFF + P1_SZ;
    static constexpr size_t P23_SZ = (size_t)NCLS * CH * (DOUT + 1) * NB;
    static constexpr size_t P3_OFF = P2_OFF + P23_SZ;
    static constexpr size_t VA_OFF = P3_OFF + P23_SZ;
    static constexpr size_t V_SZ   = (size_t)NCLS * DOUT * NB;
    static constexpr size_t VB_OFF = VA_OFF + V_SZ;
    static constexpr size_t TOTAL  = VB_OFF + V_SZ;
};

#define WAITV(N) asm volatile("s_waitcnt vmcnt(" #N ")" ::: "memory")
#define SB() __builtin_amdgcn_sched_barrier(0)
#define AS1 __attribute__((address_space(1)))
#define AS3 __attribute__((address_space(3)))

__device__ __forceinline__ half8 bch8(const void* p) {
    return *reinterpret_cast<const half8*>(p);
}

// ---- prep_fused: part 1 = squash(x)->fp16 xsh[n][b]; part 2 = W->w2t fp16.
constexpr int XWORK = NCAP * NB;
constexpr int WWORK = NCLS * NCAP * DOUT;
__global__ __launch_bounds__(256) void prep_fused(const float* __restrict__ x,
                                                  const float* __restrict__ W,
                                                  float* __restrict__ xsh,
                                                  float* __restrict__ w2t) {
    const int t = blockIdx.x * 256 + threadIdx.x;
    if (t < XWORK) {
        const int n = t >> 6;
        const int b = t & 63;
        const float4* xp = reinterpret_cast<const float4*>(x + ((size_t)b * NCAP + n) * DIN);
        float4 a = xp[0], c4 = xp[1];
        float sq = a.x*a.x + a.y*a.y + a.z*a.z + a.w*a.w
                 + c4.x*c4.x + c4.y*c4.y + c4.z*c4.z + c4.w*c4.w;
        float sc = sq / ((1.0f + sq) * sqrtf(sq));
        half8 h = {(half_t)(a.x*sc),  (half_t)(a.y*sc),  (half_t)(a.z*sc),  (half_t)(a.w*sc),
                   (half_t)(c4.x*sc), (half_t)(c4.y*sc), (half_t)(c4.z*sc), (half_t)(c4.w*sc)};
        reinterpret_cast<half8*>(xsh)[t] = h;
    } else if (t < XWORK + WWORK) {
        const int u   = t - XWORK;
        const int c   = u / (NCAP * DOUT);
        const int rem = u % (NCAP * DOUT);
        const int n   = rem >> 4;
        const int o   = rem & 15;
        const float* src = W + ((size_t)(c * NCAP + n) * DIN) * DOUT + o;
        half8 h;
#pragma unroll
        for (int i = 0; i < DIN; ++i) h[i] = (half_t)src[i * DOUT];
        half_t* dst = reinterpret_cast<half_t*>(w2t) +
                      ((size_t)(c * DOUT + o) * NCAP + n) * DIN;
        *reinterpret_cast<half8*>(dst) = h;
    }
}

// ---- sweep_m: MFMA sweep. MODE 1: dense. MODE 2: V=V1. MODE 3: V=V1+v2.
// Prologue is array-free (rule #20): sq via scalar accumulation, the 4
// per-grp V components via runtime ADDRESS arithmetic into Vf[r].
template<int MODE, int CH>
__global__ __launch_bounds__(256, 4) void sweep_m(const float* __restrict__ xsh,
                                                  const float* __restrict__ w2t,
                                                  float* __restrict__ P,
                                                  const float* __restrict__ Acc1,
                                                  const float* __restrict__ Acc2) {
    constexpr bool WEIGHTED = (MODE >= 2);
    constexpr int NPC = NCAP / CH;
    constexpr int KS  = NPC / 4;
    static_assert(KS * 4 == NPC, "geometry");

    const int bgid = blockIdx.x;     // = c*CH + ch
    const int c    = bgid / CH;
    const int ch   = bgid % CH;
    const int lane = threadIdx.x & 63;
    const int w    = threadIdx.x >> 6;
    const int grp  = lane >> 4;
    const int li   = lane & 15;
    const int bidx = w * 16 + li;

    const half_t* wb = reinterpret_cast<const half_t*>(w2t) +
                       (size_t)(c * DOUT + li) * (NCAP * DIN);
    const half_t* xb = reinterpret_cast<const half_t*>(xsh);
    const int nb0 = ch * NPC;

    // prologue: rebuild V from Acc — NO arrays, only scalars + addr arithmetic
    float Vf[4];
    if (WEIGHTED) {
        const float* a1 = Acc1 + (size_t)c * DOUT * NB + bidx;
        constexpr float invn = 1.0f / (float)NCAP;
        float sq1 = 0.f;
#pragma unroll
        for (int o = 0; o < DOUT; ++o) {
            const float v = a1[(size_t)o * NB] * invn;
            sq1 = fmaf(v, v, sq1);
        }
        const float sc1 = sq1 / ((1.0f + sq1) * sqrtf(sq1));
#pragma unroll
        for (int r = 0; r < 4; ++r)
            Vf[r] = a1[(size_t)(grp * 4 + r) * NB] * invn * sc1;
        if (MODE == 3) {
            const float* a2 = Acc2 + (size_t)c * (DOUT + 1) * NB + bidx;
            const float rz = 1.0f / a2[(size_t)DOUT * NB];
            float sq2 = 0.f;
#pragma unroll
            for (int o = 0; o < DOUT; ++o) {
                const float v = a2[(size_t)o * NB] * rz;
                sq2 = fmaf(v, v, sq2);
            }
            const float sc2 = sq2 / ((1.0f + sq2) * sqrtf(sq2));
#pragma unroll
            for (int r = 0; r < 4; ++r)
                Vf[r] = fmaf(a2[(size_t)(grp * 4 + r) * NB] * rz, sc2, Vf[r]);
        }
    }

    auto LDA = [&](int ks) -> half8 {
        return bch8(wb + (size_t)(nb0 + ks * 4 + grp) * DIN);
    };
    auto LDX = [&](int ks) -> half8 {
        return bch8(xb + ((size_t)(nb0 + ks * 4 + grp) * NB + bidx) * DIN);
    };

    f32x4 S = {0.f, 0.f, 0.f, 0.f};
    float Z = 0.f;
    const half8 hz = {};
    const f32x4 fz = {0.f, 0.f, 0.f, 0.f};

    half8 a_c = LDA(0), x_c = LDX(0);
    half8 a_n = a_c, x_n = x_c;

#pragma unroll 1
    for (int ks = 0; ks < KS; ++ks) {
        if (ks + 1 < KS) { a_n = LDA(ks + 1); x_n = LDX(ks + 1); }
        if (!WEIGHTED) {
            S = __builtin_amdgcn_mfma_f32_16x16x32_f16(a_c, x_c, S, 0, 0, 0);
        } else {
            f32x4 u0 = __builtin_amdgcn_mfma_f32_16x16x32_f16(a_c, (grp == 0) ? x_c : hz, fz, 0, 0, 0);
            f32x4 u1 = __builtin_amdgcn_mfma_f32_16x16x32_f16(a_c, (grp == 1) ? x_c : hz, fz, 0, 0, 0);
            f32x4 u2 = __builtin_amdgcn_mfma_f32_16x16x32_f16(a_c, (grp == 2) ? x_c : hz, fz, 0, 0, 0);
            f32x4 u3 = __builtin_amdgcn_mfma_f32_16x16x32_f16(a_c, (grp == 3) ? x_c : hz, fz, 0, 0, 0);

            float p0 = u0[0] * Vf[0], p1 = u1[0] * Vf[0],
                  p2 = u2[0] * Vf[0], p3 = u3[0] * Vf[0];
#pragma unroll
            for (int r = 1; r < 4; ++r) {
                p0 = fmaf(u0[r], Vf[r], p0);
                p1 = fmaf(u1[r], Vf[r], p1);
                p2 = fmaf(u2[r], Vf[r], p2);
                p3 = fmaf(u3[r], Vf[r], p3);
            }
            p0 += __shfl_xor(p0, 16); p1 += __shfl_xor(p1, 16);
            p2 += __shfl_xor(p2, 16); p3 += __shfl_xor(p3, 16);
            p0 += __shfl_xor(p0, 32); p1 += __shfl_xor(p1, 32);
            p2 += __shfl_xor(p2, 32); p3 += __shfl_xor(p3, 32);

            const float g0 = __expf(p0);
            const float g1 = __expf(p1);
            const float g2 = __expf(p2);
            const float g3 = __expf(p3);
#pragma unroll
            for (int r = 0; r < 4; ++r) {
                float s = S[r];
                s = fmaf(g0, u0[r], s);
                s = fmaf(g1, u1[r], s);
                s = fmaf(g2, u2[r], s);
                s = fmaf(g3, u3[r], s);
                S[r] = s;
            }
            Z += (g0 + g1) + (g2 + g3);
        }
        a_c = a_n; x_c = x_n;
    }

    if (!WEIGHTED) {
#pragma unroll
        for (int r = 0; r < 4; ++r)
            P[((size_t)bgid * DOUT + (grp * 4 + r)) * NB + bidx] = S[r];
    } else {
#pragma unroll
        for (int r = 0; r < 4; ++r)
            P[((size_t)bgid * (DOUT + 1) + (grp * 4 + r)) * NB + bidx] = S[r];
        if (grp == 0)
            P[((size_t)bgid * (DOUT + 1) + DOUT) * NB + bidx] = Z;
    }
}

// ---- reduce_p: stage-1 merge. Block = one (c, slot); lane = b (coalesced).
template<int SLOTS, int CH>
__global__ __launch_bounds__(64) void reduce_p(const float* __restrict__ P,
                                               float* __restrict__ Acc) {
    const int blk  = blockIdx.x;          // c*SLOTS + slot
    const int c    = blk / SLOTS;
    const int slot = blk % SLOTS;
    const int b    = threadIdx.x;
    const float* base = P + ((size_t)c * CH * SLOTS + slot) * NB + b;
    float acc = 0.f;
#pragma unroll
    for (int k = 0; k < CH; ++k) acc += base[(size_t)k * SLOTS * NB];
    Acc[(size_t)blk * NB + b] = acc;
}

// ---- final_lite: Acc3 -> v3, leaky^2, per-batch normalize
__global__ __launch_bounds__(256) void final_lite(const float* __restrict__ Acc3,
                                                  float* __restrict__ out) {
    const int b    = blockIdx.x;
    const int tid  = threadIdx.x;
    const int c    = tid >> 1;
    const int half = tid & 1;
    const float* base = Acc3 + (size_t)c * (DOUT + 1) * NB + b;

    const float rz = 1.0f / base[(size_t)DOUT * NB];

    float s[8];
    float sqh = 0.f;
#pragma unroll
    for (int j = 0; j < 8; ++j) {
        float v = base[(size_t)(half * 8 + j) * NB] * rz;
        s[j] = v;
        sqh += v * v;
    }
    const float sq = sqh + __shfl_xor(sqh, 1);
    const float sc = sq / ((1.0f + sq) * sqrtf(sq));

    float val[8];
    float ps = 0.f;
#pragma unroll
    for (int j = 0; j < 8; ++j) {
        const float v = s[j] * sc;
        const float l = v > 0.f ? v : 0.01f * v;
        val[j] = l * l;
        ps += val[j];
    }
#pragma unroll
    for (int off = 1; off < 64; off <<= 1) ps += __shfl_xor(ps, off);
    __shared__ float wsum[4];
    if ((tid & 63) == 0) wsum[tid >> 6] = ps;
    __syncthreads();
    const float inv = 1.0f / (wsum[0] + wsum[1] + wsum[2] + wsum[3]);
#pragma unroll
    for (int j = 0; j < 8; ++j)
        out[((size_t)b * NCLS + c) * DOUT + half * 8 + j] = val[j] * inv;
}

// ================= fp32 fallback path (R9, proven) =================
constexpr int NW        = 8;
constexpr int SWEEP_BLK = NW * 64;
constexpr int STG       = 4096;

__global__ __launch_bounds__(256) void prep_kernel(const float* __restrict__ x,
                                                   float* __restrict__ xs) {
    const int g = blockIdx.x * 256 + threadIdx.x;
    const int n = g >> 6;
    const int b = g & 63;
    const float4* xp = reinterpret_cast<const float4*>(x + ((size_t)b * NCAP + n) * DIN);
    float4 a = xp[0], c4 = xp[1];
    float sq = a.x*a.x + a.y*a.y + a.z*a.z + a.w*a.w
             + c4.x*c4.x + c4.y*c4.y + c4.z*c4.z + c4.w*c4.w;
    float sc = sq / ((1.0f + sq) * sqrtf(sq));
    float4 o0 = {a.x*sc,  a.y*sc,  a.z*sc,  a.w*sc};
    float4 o1 = {c4.x*sc, c4.y*sc, c4.z*sc, c4.w*sc};
    float4* op = reinterpret_cast<float4*>(xs + (size_t)g * DIN);
    op[0] = o0;
    op[1] = o1;
}

template<bool WEIGHTED, int CH>
__global__ __launch_bounds__(SWEEP_BLK, 2) void sweep_kernel(const float* __restrict__ xs,
                                                             const float* __restrict__ W,
                                                             float* __restrict__ P,
                                                             const float* __restrict__ vbuf) {
    constexpr int NPC    = NCAP / CH;
    constexpr int NPW    = NPC / NW;
    constexpr int NPAIRS = NPW / 2;

    const int bg = blockIdx.x;
    const int c  = bg / CH;
    const int ch = bg % CH;
    const int b  = threadIdx.x & 63;
    const int w  = threadIdx.x >> 6;

    __shared__ __align__(16) char smem[NW * (DOUT + 1) * NB * 4];

    float V[DOUT];
    if (WEIGHTED) {
        const float* vb = vbuf + (size_t)c * DOUT * NB + b;
#pragma unroll
        for (int o = 0; o < DOUT; ++o) V[o] = vb[o * NB];
    }

    float S[DOUT];
#pragma unroll
    for (int o = 0; o < DOUT; ++o) S[o] = 0.f;
    float Z = 0.f;

    const int n0 = ch * NPC + w * NPW;
    const char* wsrc = (const char*)W + ((size_t)c * NCAP + n0) * 512;
    char* mybuf = smem + w * STG;

    auto STAGE = [&](int p) {
        __builtin_amdgcn_global_load_lds(
            (const AS1 void*)(wsrc + (size_t)p * 1024 + b * 16),
            (AS3 void*)(mybuf + (p & 3) * 1024), 16, 0, 0);
    };
    auto XROW = [&](int row, float4& xa, float4& xb) {
        const float4* xp = reinterpret_cast<const float4*>(
            xs + ((size_t)(n0 + row) * NB + b) * DIN);
        xa = xp[0];
        xb = xp[1];
    };
    auto ROW = [&](int p, int r, float4 xa, float4 xb) {
        const float4* wl = reinterpret_cast<const float4*>(mybuf + (p & 3) * 1024 + r * 512);
        const float xv[DIN] = {xa.x, xa.y, xa.z, xa.w, xb.x, xb.y, xb.z, xb.w};
        if (!WEIGHTED) {
#pragma unroll
            for (int i = 0; i < DIN; ++i) {
                float4 q0 = wl[i*4+0], q1 = wl[i*4+1], q2 = wl[i*4+2], q3 = wl[i*4+3];
                const float xi = xv[i];
                S[ 0]=fmaf(xi,q0.x,S[ 0]); S[ 1]=fmaf(xi,q0.y,S[ 1]);
                S[ 2]=fmaf(xi,q0.z,S[ 2]); S[ 3]=fmaf(xi,q0.w,S[ 3]);
                S[ 4]=fmaf(xi,q1.x,S[ 4]); S[ 5]=fmaf(xi,q1.y,S[ 5]);
                S[ 6]=fmaf(xi,q1.z,S[ 6]); S[ 7]=fmaf(xi,q1.w,S[ 7]);
                S[ 8]=fmaf(xi,q2.x,S[ 8]); S[ 9]=fmaf(xi,q2.y,S[ 9]);
                S[10]=fmaf(xi,q2.z,S[10]); S[11]=fmaf(xi,q2.w,S[11]);
                S[12]=fmaf(xi,q3.x,S[12]); S[13]=fmaf(xi,q3.y,S[13]);
                S[14]=fmaf(xi,q3.z,S[14]); S[15]=fmaf(xi,q3.w,S[15]);
            }
        } else {
            float u[DOUT];
#pragma unroll
            for (int o = 0; o < DOUT; ++o) u[o] = 0.f;
#pragma unroll
            for (int i = 0; i < DIN; ++i) {
                float4 q0 = wl[i*4+0], q1 = wl[i*4+1], q2 = wl[i*4+2], q3 = wl[i*4+3];
                const float xi = xv[i];
                u[ 0]=fmaf(xi,q0.x,u[ 0]); u[ 1]=fmaf(xi,q0.y,u[ 1]);
                u[ 2]=fmaf(xi,q0.z,u[ 2]); u[ 3]=fmaf(xi,q0.w,u[ 3]);
                u[ 4]=fmaf(xi,q1.x,u[ 4]); u[ 5]=fmaf(xi,q1.y,u[ 5]);
                u[ 6]=fmaf(xi,q1.z,u[ 6]); u[ 7]=fmaf(xi,q1.w,u[ 7]);
                u[ 8]=fmaf(xi,q2.x,u[ 8]); u[ 9]=fmaf(xi,q2.y,u[ 9]);
                u[10]=fmaf(xi,q2.z,u[10]); u[11]=fmaf(xi,q2.w,u[11]);
                u[12]=fmaf(xi,q3.x,u[12]); u[13]=fmaf(xi,q3.y,u[13]);
                u[14]=fmaf(xi,q3.z,u[14]); u[15]=fmaf(xi,q3.w,u[15]);
            }
            float bd = 0.f;
#pragma unroll
            for (int o = 0; o < DOUT; ++o) bd = fmaf(u[o], V[o], bd);
            const float g = __expf(bd);
            Z += g;
#pragma unroll
            for (int o = 0; o < DOUT; ++o) S[o] = fmaf(g, u[o], S[o]);
        }
    };

    STAGE(0); SB();
    STAGE(1); SB();
    float4 ca0, ca1, cb0, cb1, na0, na1, nb0, nb1;
    XROW(0, ca0, ca1);
    XROW(1, cb0, cb1);
    SB();

#pragma unroll 1
    for (int p = 0; p < NPAIRS; ++p) {
        if (p + 2 < NPAIRS) STAGE(p + 2);
        SB();
        if (p + 1 < NPAIRS) {
            XROW(2 * (p + 1),     na0, na1);
            XROW(2 * (p + 1) + 1, nb0, nb1);
        }
        SB();
        if (p < NPAIRS - 2)       { WAITV(5); }
        else if (p == NPAIRS - 2) { WAITV(4); }
        else                      { WAITV(0); }
        SB();
        ROW(p, 0, ca0, ca1);
        ROW(p, 1, cb0, cb1);
        ca0 = na0; ca1 = na1; cb0 = nb0; cb1 = nb1;
    }

    __syncthreads();
    float (*red)[DOUT + 1][NB] = reinterpret_cast<float (*)[DOUT + 1][NB]>(smem);
#pragma unroll
    for (int o = 0; o < DOUT; ++o) red[w][o][b] = S[o];
    red[w][DOUT][b] = Z;
    __syncthreads();
    for (int idx = threadIdx.x; idx < (DOUT + 1) * NB; idx += SWEEP_BLK) {
        const int slot = idx >> 6;
        const int bb   = idx & 63;
        float acc = 0.f;
#pragma unroll
        for (int k = 0; k < NW; ++k) acc += red[k][slot][bb];
        if (!WEIGHTED) {
            if (slot < DOUT)
                P[((size_t)bg * DOUT + slot) * NB + bb] = acc;
        } else {
            P[((size_t)bg * (DOUT + 1) + slot) * NB + bb] = acc;
        }
    }
}

template<int MODE, int CH>
__global__ __launch_bounds__(64) void vupd_kernel(const float* __restrict__ P,
                                                  const float* __restrict__ vin,
                                                  float* __restrict__ vout) {
    const int c = blockIdx.x;
    const int b = threadIdx.x;

    float s[DOUT];
    float sq = 0.f;
    if (MODE == 1) {
#pragma unroll
        for (int o = 0; o < DOUT; ++o) {
            float acc = 0.f;
#pragma unroll
            for (int k = 0; k < CH; ++k)
                acc += P[(((size_t)c * CH + k) * DOUT + o) * NB + b];
            acc *= (1.0f / (float)NCAP);
            s[o] = acc;
            sq += acc * acc;
        }
    } else {
        float Zt = 0.f;
#pragma unroll
        for (int k = 0; k < CH; ++k)
            Zt += P[(((size_t)c * CH + k) * (DOUT + 1) + DOUT) * NB + b];
        const float rz = 1.0f / Zt;
#pragma unroll
        for (int o = 0; o < DOUT; ++o) {
            float acc = 0.f;
#pragma unroll
            for (int k = 0; k < CH; ++k)
                acc += P[(((size_t)c * CH + k) * (DOUT + 1) + o) * NB + b];
            acc *= rz;
            s[o] = acc;
            sq += acc * acc;
        }
    }
    const float sc = sq / ((1.0f + sq) * sqrtf(sq));
#pragma unroll
    for (int o = 0; o < DOUT; ++o) {
        float v = s[o] * sc;
        if (MODE == 2) v += vin[((size_t)c * DOUT + o) * NB + b];
        vout[((size_t)c * DOUT + o) * NB + b] = v;
    }
}

template<int CH>
__global__ __launch_bounds__(256) void final_kernel(const float* __restrict__ P3,
                                                    float* __restrict__ out) {
    const int b    = blockIdx.x;
    const int tid  = threadIdx.x;
    const int c    = tid >> 1;
    const int half = tid & 1;

    float Zt = 0.f;
#pragma unroll
    for (int k = 0; k < CH; ++k)
        Zt += P3[(((size_t)c * CH + k) * (DOUT + 1) + DOUT) * NB + b];
    const float rz = 1.0f / Zt;

    float s[8];
    float sqh = 0.f;
#pragma unroll
    for (int j = 0; j < 8; ++j) {
        const int o = half * 8 + j;
        float acc = 0.f;
#pragma unroll
        for (int k = 0; k < CH; ++k)
            acc += P3[(((size_t)c * CH + k) * (DOUT + 1) + o) * NB + b];
        acc *= rz;
        s[j] = acc;
        sqh += acc * acc;
    }
    const float sq = sqh + __shfl_xor(sqh, 1);
    const float sc = sq / ((1.0f + sq) * sqrtf(sq));

    float val[8];
    float ps = 0.f;
#pragma unroll
    for (int j = 0; j < 8; ++j) {
        const float v = s[j] * sc;
        const float l = v > 0.f ? v : 0.01f * v;
        val[j] = l * l;
        ps += val[j];
    }
#pragma unroll
    for (int off = 1; off < 64; off <<= 1) ps += __shfl_xor(ps, off);
    __shared__ float wsum[4];
    if ((tid & 63) == 0) wsum[tid >> 6] = ps;
    __syncthreads();
    const float inv = 1.0f / (wsum[0] + wsum[1] + wsum[2] + wsum[3]);
#pragma unroll
    for (int j = 0; j < 8; ++j)
        out[((size_t)b * NCLS + c) * DOUT + half * 8 + j] = val[j] * inv;
}

template<int CH>
static void run_f32(const float* x, const float* W, float* out, float* ws,
                    hipStream_t stream) {
    using L = Layout<CH>;
    float* xs = ws + L::XS_OFF;
    float* P1 = ws + L::P1_OFF;
    float* P2 = ws + L::P2_OFF;
    float* P3 = ws + L::P3_OFF;
    float* VA = ws + L::VA_OFF;
    float* VB = ws + L::VB_OFF;

    hipLaunchKernelGGL(prep_kernel, dim3(NCAP * NB / 256), dim3(256), 0, stream, x, xs);
    hipLaunchKernelGGL((sweep_kernel<false, CH>), dim3(NCLS * CH), dim3(SWEEP_BLK), 0,
                       stream, xs, W, P1, nullptr);
    hipLaunchKernelGGL((vupd_kernel<1, CH>), dim3(NCLS), dim3(64), 0, stream,
                       P1, nullptr, VA);
    hipLaunchKernelGGL((sweep_kernel<true, CH>), dim3(NCLS * CH), dim3(SWEEP_BLK), 0,
                       stream, xs, W, P2, VA);
    hipLaunchKernelGGL((vupd_kernel<2, CH>), dim3(NCLS), dim3(64), 0, stream,
                       P2, VA, VB);
    hipLaunchKernelGGL((sweep_kernel<true, CH>), dim3(NCLS * CH), dim3(SWEEP_BLK), 0,
                       stream, xs, W, P3, VB);
    hipLaunchKernelGGL((final_kernel<CH>), dim3(NB), dim3(256), 0, stream, P3, out);
}

extern "C" void kernel_launch(void* const* d_in, const int* in_sizes, int n_in,
                              void* d_out, int out_size, void* d_ws, size_t ws_size,
                              hipStream_t stream) {
    const float* x = (const float*)d_in[0];
    const float* W = (const float*)d_in[1];
    float* out = (float*)d_out;
    float* ws  = (float*)d_ws;

    if (ws_size >= LM::TOTAL * sizeof(float)) {
        float* xsh = ws + LM::XSH_OFF;
        float* w2t = ws + LM::W2T_OFF;
        float* P1  = ws + LM::P1_OFF;
        float* P2  = ws + LM::P2_OFF;
        float* P3  = ws + LM::P3_OFF;
        float* A1  = ws + LM::A1_OFF;
        float* A2  = ws + LM::A2_OFF;
        float* A3  = ws + LM::A3_OFF;

        hipLaunchKernelGGL(prep_fused, dim3((XWORK + WWORK + 255) / 256), dim3(256), 0,
                           stream, x, W, xsh, w2t);
        hipLaunchKernelGGL((sweep_m<1, CHM>), dim3(NCLS * CHM), dim3(256), 0,
                           stream, xsh, w2t, P1, nullptr, nullptr);
        hipLaunchKernelGGL((reduce_p<DOUT, CHM>), dim3(NCLS * DOUT), dim3(64), 0,
                           stream, P1, A1);
        hipLaunchKernelGGL((sweep_m<2, CHM>), dim3(NCLS * CHM), dim3(256), 0,
                           stream, xsh, w2t, P2, A1, nullptr);
        hipLaunchKernelGGL((reduce_p<DOUT + 1, CHM>), dim3(NCLS * (DOUT + 1)), dim3(64), 0,
                           stream, P2, A2);
        hipLaunchKernelGGL((sweep_m<3, CHM>), dim3(NCLS * CHM), dim3(256), 0,
                           stream, xsh, w2t, P3, A1, A2);
        hipLaunchKernelGGL((reduce_p<DOUT + 1, CHM>), dim3(NCLS * (DOUT + 1)), dim3(64), 0,
                           stream, P3, A3);
        hipLaunchKernelGGL(final_lite, dim3(NB), dim3(256), 0, stream, A3, out);
    } else if (ws_size >= Layout<8>::TOTAL * sizeof(float)) {
        run_f32<8>(x, W, out, ws, stream);
    } else {
        run_f32<4>(x, W, out, ws, stream);
    }
}